// Round 6
// baseline (151.717 us; speedup 1.0000x reference)
//
#include <hip/hip_runtime.h>
#include <hip/hip_cooperative_groups.h>

namespace cg = cooperative_groups;

#define N_COLS 3072
#define N_ROWS 3072
#define N_CH   3
#define NPIX   (N_COLS * N_ROWS)          // 9,437,184  (fits int)
#define NTOT   (N_CH * NPIX)              // 28,311,552 (fits int)
#define BLOCKS  1024
#define THREADS 256
#define CHUNKS  16                        // BLOCKS/64; 16*256=4096 >= max nsteps 3071

// One cooperative kernel:
//  Phase 1: float4 copy inp->out + per-block max partials (round-2 copy
//           config, measured ~6.9 TB/s). Every partial slot written
//           unconditionally each call -> replay-safe.
//  grid.sync()
//  Phase 2: block (crack b = blk&63, chunk = blk>>6) paints steps
//           k = chunk*256+tid of crack b via the closed-form Bresenham:
//           for dx>=dy the x-advance fires every step (invariant 2*err>-dy),
//           so step k paints (x0+sx*k, y0+sy*ck),
//           ck = max(0, ceil((2k*dy-dx)/(2dx))); nsteps=max(dx,dy); the
//           endpoint (k=nsteps) is NOT painted (done-after-move). Mirrored
//           for dy>dx. Verified against the reference recurrence on
//           (3,2),(4,1),(1,4),(5,3),(3,3),(2,1),(1,2),(n,0).
__global__ __launch_bounds__(THREADS)
void fused_kernel(const float* __restrict__ in, float* __restrict__ out,
                  float* __restrict__ partial,
                  const int* __restrict__ x_start, const int* __restrict__ x_end,
                  const int* __restrict__ y_start, const int* __restrict__ y_end,
                  const int* __restrict__ length,  const int* __restrict__ width) {
    // ---- Phase 1: copy + max ----
    const float4* in4  = (const float4*)in;
    float4*       out4 = (float4*)out;
    const int n4 = NTOT / 4;   // 7,077,888
    float m = -INFINITY;
    for (int i = blockIdx.x * blockDim.x + threadIdx.x; i < n4;
         i += gridDim.x * blockDim.x) {
        float4 v = in4[i];
        out4[i] = v;
        m = fmaxf(m, fmaxf(fmaxf(v.x, v.y), fmaxf(v.z, v.w)));
    }
    #pragma unroll
    for (int off = 32; off > 0; off >>= 1)
        m = fmaxf(m, __shfl_down(m, off, 64));
    __shared__ float smax[THREADS / 64];
    const int lane = threadIdx.x & 63;
    const int wid  = threadIdx.x >> 6;
    if (lane == 0) smax[wid] = m;
    __syncthreads();
    if (threadIdx.x == 0) {
        float r = smax[0];
        #pragma unroll
        for (int w = 1; w < THREADS / 64; ++w) r = fmaxf(r, smax[w]);
        partial[blockIdx.x] = r;
    }

    cg::this_grid().sync();   // all copies + partials visible device-wide

    // ---- Phase 2: paint ----
    const int b = blockIdx.x & 63;           // crack id
    const int chunk = blockIdx.x >> 6;       // step chunk

    const int x0 = x_start[b], x1 = x_end[b];
    const int y0 = y_start[b], y1 = y_end[b];
    if (x0 == x1 && y0 == y1) return;        // done0: paints nothing

    const int dx = abs(x1 - x0), dy = abs(y1 - y0);
    const int nsteps = max(dx, dy);
    if (chunk * THREADS >= nsteps) return;   // block-uniform exit

    // Wave-redundant reduction of the 1024 partials (L2-resident).
    float g = -INFINITY;
    #pragma unroll
    for (int i = 0; i < BLOCKS / 64; ++i) g = fmaxf(g, partial[lane + i * 64]);
    #pragma unroll
    for (int off = 32; off > 0; off >>= 1)
        g = fmaxf(g, __shfl_down(g, off, 64));
    const float val = __shfl(g, 0, 64);

    const int k = chunk * THREADS + threadIdx.x;
    if (k >= nsteps) return;

    const int sx = (x0 < x1) ? 1 : -1;
    const int sy = (y0 < y1) ? 1 : -1;
    int X, Y;
    if (dx >= dy) {
        X = k;
        const int num = 2 * k * dy - dx;
        Y = (num <= 0) ? 0 : (num + 2 * dx - 1) / (2 * dx);
    } else {
        Y = k;
        const int num = 2 * k * dx - dy;
        X = (num <= 0) ? 0 : (num + 2 * dy - 1) / (2 * dy);
    }
    const int px = x0 + sx * X;
    const int py = y0 + sy * Y;

    // Clamped stamp bounds: no per-pixel divergent checks. 32-bit offsets.
    const int Wv = min(width[b],  N_COLS - py);
    const int Lv = min(length[b], N_ROWS - px);
    for (int dw = 0; dw < Wv; ++dw) {
        const int rowp = (py + dw) * N_ROWS + px;
        for (int dl = 0; dl < Lv; ++dl) {
            out[rowp + dl]            = val;
            out[NPIX + rowp + dl]     = val;
            out[2 * NPIX + rowp + dl] = val;
        }
    }
}

extern "C" void kernel_launch(void* const* d_in, const int* in_sizes, int n_in,
                              void* d_out, int out_size, void* d_ws, size_t ws_size,
                              hipStream_t stream) {
    const float* inp     = (const float*)d_in[0];
    const int*   x_start = (const int*)d_in[1];
    const int*   x_end   = (const int*)d_in[2];
    const int*   y_start = (const int*)d_in[3];
    const int*   y_end   = (const int*)d_in[4];
    const int*   length  = (const int*)d_in[5];
    const int*   width   = (const int*)d_in[6];
    float*       out     = (float*)d_out;
    float*       partial = (float*)d_ws;   // BLOCKS floats

    void* args[] = { (void*)&inp, (void*)&out, (void*)&partial,
                     (void*)&x_start, (void*)&x_end,
                     (void*)&y_start, (void*)&y_end,
                     (void*)&length, (void*)&width };
    hipLaunchCooperativeKernel((const void*)fused_kernel,
                               dim3(BLOCKS), dim3(THREADS), args, 0, stream);
}

// Round 7
// 115.432 us; speedup vs baseline: 1.3143x; 1.3143x over previous
//
#include <hip/hip_runtime.h>

#define N_COLS 3072
#define N_ROWS 3072
#define NPIX   (N_COLS * N_ROWS)          // 9,437,184  (fits int)
#define NTOT   (3 * NPIX)                 // 28,311,552 (fits int)
#define BLOCKS   1024
#define THREADS  256
#define PAINTERS 64                       // last 64 ticket-holders paint
#define CHUNKS   12                       // 12*256 = 3072 >= max nsteps (3071)
#define UNITS    (CHUNKS * 64 * 3)        // (chunk, crack, channel) work units = 2304
#define UNITS_PER_PAINTER (UNITS / PAINTERS)  // 36

// Single fused kernel, REGULAR launch (cooperative launch mode collapsed BW
// to ~1.1 TB/s in round 6 — launch-mode coherence penalty, avoided here).
//
// Phase 1: float4 grid-stride copy in->out + per-block max partial (round-2
//   config, measured ~6.9 TB/s). Partials written unconditionally.
// Ticket:  __threadfence + atomicAdd on counter (zeroed per call by a 4-byte
//   hipMemsetAsync). Blocks with ticket < BLOCKS-PAINTERS exit.
// Phase 2: the last 64 arrivals (already resident -> spin is deadlock-free:
//   non-painters never wait) spin to counter==BLOCKS (acquire), reduce the
//   partials, and paint. Closed-form Bresenham: for dx>=dy the x-advance
//   fires every step (invariant 2*err > -dy), so step k paints
//   (x0+sx*k, y0+sy*ck), ck = max(0, ceil((2k*dy-dx)/(2dx)));
//   nsteps = max(dx,dy); endpoint (k==nsteps) NOT painted (done-after-move).
//   Mirrored for dy>dx. Verified against the reference recurrence on
//   (3,2),(4,1),(1,4),(5,3),(3,3),(2,1),(1,2),(n,0); passed rounds 2,4,5.
__global__ __launch_bounds__(THREADS)
void fused_kernel(const float* __restrict__ in, float* __restrict__ out,
                  unsigned* __restrict__ counter, float* __restrict__ partial,
                  const int* __restrict__ x_start, const int* __restrict__ x_end,
                  const int* __restrict__ y_start, const int* __restrict__ y_end,
                  const int* __restrict__ length,  const int* __restrict__ width) {
    // ---- Phase 1: copy + max ----
    const float4* in4  = (const float4*)in;
    float4*       out4 = (float4*)out;
    const int n4 = NTOT / 4;   // 7,077,888
    float m = -INFINITY;
    for (int i = blockIdx.x * THREADS + threadIdx.x; i < n4; i += BLOCKS * THREADS) {
        float4 v = in4[i];
        out4[i] = v;
        m = fmaxf(m, fmaxf(fmaxf(v.x, v.y), fmaxf(v.z, v.w)));
    }
    #pragma unroll
    for (int off = 32; off > 0; off >>= 1)
        m = fmaxf(m, __shfl_down(m, off, 64));
    __shared__ float smax[THREADS / 64];
    __shared__ unsigned s_old;
    const int lane = threadIdx.x & 63;
    const int wid  = threadIdx.x >> 6;
    if (lane == 0) smax[wid] = m;
    __syncthreads();
    if (threadIdx.x == 0) {
        float r = fmaxf(fmaxf(smax[0], smax[1]), fmaxf(smax[2], smax[3]));
        partial[blockIdx.x] = r;
        __threadfence();   // publish partial + this block's copy stores
        s_old = __hip_atomic_fetch_add(counter, 1u, __ATOMIC_ACQ_REL,
                                       __HIP_MEMORY_SCOPE_AGENT);
    }
    __syncthreads();
    const unsigned old = s_old;
    if (old < BLOCKS - PAINTERS) return;     // block-uniform: non-painters leave

    // ---- wait for all 1024 tickets (painters are already resident) ----
    if (threadIdx.x == 0) {
        while (__hip_atomic_load(counter, __ATOMIC_ACQUIRE,
                                 __HIP_MEMORY_SCOPE_AGENT) < BLOCKS)
            __builtin_amdgcn_s_sleep(2);
    }
    __syncthreads();

    // ---- global max from partials (wave-redundant) ----
    float g = -INFINITY;
    #pragma unroll
    for (int i = 0; i < BLOCKS / 64; ++i) g = fmaxf(g, partial[lane + i * 64]);
    #pragma unroll
    for (int off = 32; off > 0; off >>= 1)
        g = fmaxf(g, __shfl_down(g, off, 64));
    const float val = __shfl(g, 0, 64);

    // ---- Phase 2: paint 36 contiguous units ----
    const int rank = (int)old - (BLOCKS - PAINTERS);
    const int u0 = rank * UNITS_PER_PAINTER;
    for (int u = u0; u < u0 + UNITS_PER_PAINTER; ++u) {
        const int chunk = u % CHUNKS;        // magic-mul, compile-time const
        const int t     = u / CHUNKS;
        const int b     = t & 63;            // crack id
        const int ch    = t >> 6;            // channel

        const int x0 = x_start[b], x1 = x_end[b];
        const int y0 = y_start[b], y1 = y_end[b];
        if (x0 == x1 && y0 == y1) continue;  // done0: paints nothing

        const int dx = abs(x1 - x0), dy = abs(y1 - y0);
        const int nsteps = max(dx, dy);
        const int k = chunk * THREADS + threadIdx.x;
        if (k >= nsteps) continue;

        const int sx = (x0 < x1) ? 1 : -1;
        const int sy = (y0 < y1) ? 1 : -1;
        int X, Y;
        if (dx >= dy) {
            X = k;
            const int num = 2 * k * dy - dx;
            Y = (num <= 0) ? 0 : (num + 2 * dx - 1) / (2 * dx);
        } else {
            Y = k;
            const int num = 2 * k * dx - dy;
            X = (num <= 0) ? 0 : (num + 2 * dy - 1) / (2 * dy);
        }
        const int px = x0 + sx * X;
        const int py = y0 + sy * Y;

        const int Wv = min(width[b],  N_COLS - py);
        const int Lv = min(length[b], N_ROWS - px);
        float* chan = out + ch * NPIX;
        for (int dw = 0; dw < Wv; ++dw) {
            const int rowp = (py + dw) * N_ROWS + px;
            for (int dl = 0; dl < Lv; ++dl)
                chan[rowp + dl] = val;
        }
    }
}

extern "C" void kernel_launch(void* const* d_in, const int* in_sizes, int n_in,
                              void* d_out, int out_size, void* d_ws, size_t ws_size,
                              hipStream_t stream) {
    const float* inp     = (const float*)d_in[0];
    const int*   x_start = (const int*)d_in[1];
    const int*   x_end   = (const int*)d_in[2];
    const int*   y_start = (const int*)d_in[3];
    const int*   y_end   = (const int*)d_in[4];
    const int*   length  = (const int*)d_in[5];
    const int*   width   = (const int*)d_in[6];
    float*       out     = (float*)d_out;
    unsigned*    counter = (unsigned*)d_ws;                  // 4 bytes
    float*       partial = (float*)((char*)d_ws + 256);      // BLOCKS floats

    hipMemsetAsync(counter, 0, 4, stream);   // capturable; zero ticket each call
    fused_kernel<<<BLOCKS, THREADS, 0, stream>>>(
        inp, out, counter, partial,
        x_start, x_end, y_start, y_end, length, width);
}

// Round 8
// 50.299 us; speedup vs baseline: 3.0163x; 2.2949x over previous
//
#include <hip/hip_runtime.h>

#define N_COLS 3072
#define N_ROWS 3072
#define N_CH   3
#define NPIX   (N_COLS * N_ROWS)          // 9,437,184  (fits int)
#define NTOT   (N_CH * NPIX)              // 28,311,552 (fits int)
#define RED_BLOCKS  1024
#define RED_THREADS 256
#define COPY_ITERS  27                     // NTOT/4 / (1024*256) == 27 exactly
#define PAINT_THREADS 256
#define PAINT_CHUNKS  12   // 12*256 = 3072 >= max nsteps (3071)

// Kernel 1: copy inp -> out (float4) + global-max partials into d_ws.
// Fixed trip count: 7,077,888 float4s == 1024 blocks * 256 thr * 27 iters,
// no remainder -> no bounds compare in the hot loop. Every partial slot
// written unconditionally each call -> replay-safe. (NOTE: do NOT add
// device-scope fences/atomics here — round 6/7 showed per-block agent-scope
// publication collapses streaming-store BW ~6x on CDNA4 non-coherent L2s.)
__global__ __launch_bounds__(RED_THREADS)
void copy_max_kernel(const float* __restrict__ in, float* __restrict__ out,
                     float* __restrict__ partial) {
    const float4* in4  = (const float4*)in;
    float4*       out4 = (float4*)out;
    const int tid = blockIdx.x * RED_THREADS + threadIdx.x;   // 0..262143
    float m = -INFINITY;
    #pragma unroll 3
    for (int j = 0; j < COPY_ITERS; ++j) {
        const int i = tid + j * (RED_BLOCKS * RED_THREADS);
        float4 v = in4[i];
        out4[i] = v;
        m = fmaxf(m, fmaxf(fmaxf(v.x, v.y), fmaxf(v.z, v.w)));
    }
    #pragma unroll
    for (int off = 32; off > 0; off >>= 1)
        m = fmaxf(m, __shfl_down(m, off, 64));
    __shared__ float smax[RED_THREADS / 64];
    const int lane = threadIdx.x & 63;
    const int wid  = threadIdx.x >> 6;
    if (lane == 0) smax[wid] = m;
    __syncthreads();
    if (threadIdx.x == 0) {
        float r = fmaxf(fmaxf(smax[0], smax[1]), fmaxf(smax[2], smax[3]));
        partial[blockIdx.x] = r;
    }
}

// Kernel 2: closed-form Bresenham rasterization. One thread per line step;
// grid = (chunk, crack, channel). For dx >= dy the x-advance fires every
// step (invariant 2*err > -dy), so step k paints (x0+sx*k, y0+sy*ck),
// ck = max(0, ceil((2k*dy-dx)/(2dx))); nsteps = max(dx,dy); the endpoint
// (k == nsteps) is NOT painted (done-after-move). Mirrored for dy > dx.
// Verified against the reference recurrence on (3,2),(4,1),(1,4),(5,3),
// (3,3),(2,1),(1,2),(n,0); passed rounds 2,4,5.
__global__ __launch_bounds__(PAINT_THREADS)
void paint_kernel(const int* __restrict__ x_start, const int* __restrict__ x_end,
                  const int* __restrict__ y_start, const int* __restrict__ y_end,
                  const int* __restrict__ length,  const int* __restrict__ width,
                  float* __restrict__ out, const float* __restrict__ partial) {
    const int b  = blockIdx.y;
    const int x0 = x_start[b], x1 = x_end[b];
    const int y0 = y_start[b], y1 = y_end[b];

    if (x0 == x1 && y0 == y1) return;          // done0: paints nothing

    const int dx = abs(x1 - x0), dy = abs(y1 - y0);
    const int nsteps = max(dx, dy);
    if ((int)(blockIdx.x * PAINT_THREADS) >= nsteps) return;  // block-uniform

    // Wave-redundant reduction of the 1024 partials (L2-resident); runs with
    // all 64 lanes active (shfl), so it precedes the per-lane k check.
    const int lane = threadIdx.x & 63;
    float m = -INFINITY;
    #pragma unroll
    for (int i = 0; i < RED_BLOCKS / 64; ++i) m = fmaxf(m, partial[lane + i * 64]);
    #pragma unroll
    for (int off = 32; off > 0; off >>= 1)
        m = fmaxf(m, __shfl_down(m, off, 64));
    const float val = __shfl(m, 0, 64);

    const int k = blockIdx.x * PAINT_THREADS + threadIdx.x;
    if (k >= nsteps) return;

    const int sx = (x0 < x1) ? 1 : -1;
    const int sy = (y0 < y1) ? 1 : -1;
    int X, Y;
    if (dx >= dy) {
        X = k;
        const int num = 2 * k * dy - dx;
        Y = (num <= 0) ? 0 : (num + 2 * dx - 1) / (2 * dx);
    } else {
        Y = k;
        const int num = 2 * k * dx - dy;
        X = (num <= 0) ? 0 : (num + 2 * dy - 1) / (2 * dy);
    }
    const int px = x0 + sx * X;
    const int py = y0 + sy * Y;

    // Clamped stamp bounds: no per-pixel divergent checks. 32-bit offsets.
    const int Wv = min(width[b],  N_COLS - py);
    const int Lv = min(length[b], N_ROWS - px);
    float* chan = out + blockIdx.z * NPIX;
    for (int dw = 0; dw < Wv; ++dw) {
        const int rowp = (py + dw) * N_ROWS + px;
        for (int dl = 0; dl < Lv; ++dl)
            chan[rowp + dl] = val;
    }
}

extern "C" void kernel_launch(void* const* d_in, const int* in_sizes, int n_in,
                              void* d_out, int out_size, void* d_ws, size_t ws_size,
                              hipStream_t stream) {
    const float* inp     = (const float*)d_in[0];
    const int*   x_start = (const int*)d_in[1];
    const int*   x_end   = (const int*)d_in[2];
    const int*   y_start = (const int*)d_in[3];
    const int*   y_end   = (const int*)d_in[4];
    const int*   length  = (const int*)d_in[5];
    const int*   width   = (const int*)d_in[6];
    float*       out     = (float*)d_out;
    float*       partial = (float*)d_ws;   // RED_BLOCKS floats

    copy_max_kernel<<<RED_BLOCKS, RED_THREADS, 0, stream>>>(inp, out, partial);
    dim3 pgrid(PAINT_CHUNKS, 64, N_CH);
    paint_kernel<<<pgrid, PAINT_THREADS, 0, stream>>>(
        x_start, x_end, y_start, y_end, length, width, out, partial);
}

// Round 9
// 48.163 us; speedup vs baseline: 3.1501x; 1.0444x over previous
//
#include <hip/hip_runtime.h>

#define N_COLS 3072
#define N_ROWS 3072
#define N_CH   3
#define NPIX   (N_COLS * N_ROWS)          // 9,437,184  (fits int)
#define NTOT   (N_CH * NPIX)              // 28,311,552 (fits int)
#define RED_BLOCKS  1024
#define RED_THREADS 256
#define PAINT_THREADS 256
#define PAINT_CHUNKS  12   // 12*256 = 3072 >= max nsteps (3071)

typedef float f32x4 __attribute__((ext_vector_type(4)));  // native vec for nt-store builtin

// Kernel 1: copy inp -> out + global-max partials into d_ws.
// Round-5 loop structure (measured 46.8 us total). ONE isolated change:
// nontemporal STORES (evict-first: the 113 MB output stream stops displacing
// the input from L2/L3, so input reads become L3-hits across graph replays —
// round-8 counters showed FETCH already 55 MB < 113 MB from partial
// residency). Loads stay REGULAR (round-4's nt loads killed residency).
// Every partial slot written unconditionally each call -> replay-safe.
// (NOTE: no device-scope fences/atomics — rounds 6/7 showed per-block
// agent-scope publication collapses streaming-store BW ~6x.)
__global__ __launch_bounds__(RED_THREADS)
void copy_max_kernel(const float* __restrict__ in, float* __restrict__ out,
                     float* __restrict__ partial) {
    const f32x4* in4  = (const f32x4*)in;
    f32x4*       out4 = (f32x4*)out;
    const int n4 = NTOT / 4;   // 7,077,888
    float m = -INFINITY;
    for (int i = blockIdx.x * blockDim.x + threadIdx.x; i < n4;
         i += gridDim.x * blockDim.x) {
        f32x4 v = in4[i];                          // regular load (L3-cacheable)
        __builtin_nontemporal_store(v, &out4[i]);  // evict-first store
        m = fmaxf(m, fmaxf(fmaxf(v.x, v.y), fmaxf(v.z, v.w)));
    }
    #pragma unroll
    for (int off = 32; off > 0; off >>= 1)
        m = fmaxf(m, __shfl_down(m, off, 64));
    __shared__ float smax[RED_THREADS / 64];
    const int lane = threadIdx.x & 63;
    const int wid  = threadIdx.x >> 6;
    if (lane == 0) smax[wid] = m;
    __syncthreads();
    if (threadIdx.x == 0) {
        float r = fmaxf(fmaxf(smax[0], smax[1]), fmaxf(smax[2], smax[3]));
        partial[blockIdx.x] = r;
    }
}

// Kernel 2: closed-form Bresenham rasterization. One thread per line step;
// grid = (chunk, crack, channel). For dx >= dy the x-advance fires every
// step (invariant 2*err > -dy), so step k paints (x0+sx*k, y0+sy*ck),
// ck = max(0, ceil((2k*dy-dx)/(2dx))); nsteps = max(dx,dy); the endpoint
// (k == nsteps) is NOT painted (done-after-move). Mirrored for dy > dx.
// Verified against the reference recurrence on (3,2),(4,1),(1,4),(5,3),
// (3,3),(2,1),(1,2),(n,0); passed rounds 2,4,5,8.
__global__ __launch_bounds__(PAINT_THREADS)
void paint_kernel(const int* __restrict__ x_start, const int* __restrict__ x_end,
                  const int* __restrict__ y_start, const int* __restrict__ y_end,
                  const int* __restrict__ length,  const int* __restrict__ width,
                  float* __restrict__ out, const float* __restrict__ partial) {
    const int b  = blockIdx.y;
    const int x0 = x_start[b], x1 = x_end[b];
    const int y0 = y_start[b], y1 = y_end[b];

    if (x0 == x1 && y0 == y1) return;          // done0: paints nothing

    const int dx = abs(x1 - x0), dy = abs(y1 - y0);
    const int nsteps = max(dx, dy);
    if ((int)(blockIdx.x * PAINT_THREADS) >= nsteps) return;  // block-uniform

    // Wave-redundant reduction of the 1024 partials (L2-resident); runs with
    // all 64 lanes active (shfl), so it precedes the per-lane k check.
    const int lane = threadIdx.x & 63;
    float m = -INFINITY;
    #pragma unroll
    for (int i = 0; i < RED_BLOCKS / 64; ++i) m = fmaxf(m, partial[lane + i * 64]);
    #pragma unroll
    for (int off = 32; off > 0; off >>= 1)
        m = fmaxf(m, __shfl_down(m, off, 64));
    const float val = __shfl(m, 0, 64);

    const int k = blockIdx.x * PAINT_THREADS + threadIdx.x;
    if (k >= nsteps) return;

    const int sx = (x0 < x1) ? 1 : -1;
    const int sy = (y0 < y1) ? 1 : -1;
    int X, Y;
    if (dx >= dy) {
        X = k;
        const int num = 2 * k * dy - dx;
        Y = (num <= 0) ? 0 : (num + 2 * dx - 1) / (2 * dx);
    } else {
        Y = k;
        const int num = 2 * k * dx - dy;
        X = (num <= 0) ? 0 : (num + 2 * dy - 1) / (2 * dy);
    }
    const int px = x0 + sx * X;
    const int py = y0 + sy * Y;

    // Clamped stamp bounds: no per-pixel divergent checks. 32-bit offsets.
    const int Wv = min(width[b],  N_COLS - py);
    const int Lv = min(length[b], N_ROWS - px);
    float* chan = out + blockIdx.z * NPIX;
    for (int dw = 0; dw < Wv; ++dw) {
        const int rowp = (py + dw) * N_ROWS + px;
        for (int dl = 0; dl < Lv; ++dl)
            chan[rowp + dl] = val;
    }
}

extern "C" void kernel_launch(void* const* d_in, const int* in_sizes, int n_in,
                              void* d_out, int out_size, void* d_ws, size_t ws_size,
                              hipStream_t stream) {
    const float* inp     = (const float*)d_in[0];
    const int*   x_start = (const int*)d_in[1];
    const int*   x_end   = (const int*)d_in[2];
    const int*   y_start = (const int*)d_in[3];
    const int*   y_end   = (const int*)d_in[4];
    const int*   length  = (const int*)d_in[5];
    const int*   width   = (const int*)d_in[6];
    float*       out     = (float*)d_out;
    float*       partial = (float*)d_ws;   // RED_BLOCKS floats

    copy_max_kernel<<<RED_BLOCKS, RED_THREADS, 0, stream>>>(inp, out, partial);
    dim3 pgrid(PAINT_CHUNKS, 64, N_CH);
    paint_kernel<<<pgrid, PAINT_THREADS, 0, stream>>>(
        x_start, x_end, y_start, y_end, length, width, out, partial);
}

// Round 10
// 46.658 us; speedup vs baseline: 3.2517x; 1.0323x over previous
//
#include <hip/hip_runtime.h>

#define N_COLS 3072
#define N_ROWS 3072
#define N_CH   3
#define NPIX   (N_COLS * N_ROWS)          // 9,437,184  (fits int)
#define NTOT   (N_CH * NPIX)              // 28,311,552 (fits int)
#define RED_BLOCKS  1024
#define RED_THREADS 256
#define PAINT_THREADS 256
#define PAINT_CHUNKS  12   // 12*256 = 3072 >= max nsteps (3071)

// Kernel 1: copy inp -> out (plain cached float4) + global-max partials.
// BEST CONFIG (round 5, 46.8 us): 1024 blocks, grid-stride, regular
// loads/stores. A/B-refuted alternatives: nt load+store (R4: +15us),
// nt store only (R9: +1.4us), fixed-trip unroll (R8: +3.5us), 2048 blocks
// (R4), cooperative fusion (R6: 3x worse), ticket-fence fusion (R7: 2.5x
// worse — agent-scope publication collapses streaming-store BW on
// non-coherent per-XCD L2s). Every partial slot written unconditionally
// each call -> replay-safe.
__global__ __launch_bounds__(RED_THREADS)
void copy_max_kernel(const float* __restrict__ in, float* __restrict__ out,
                     float* __restrict__ partial) {
    const float4* in4  = (const float4*)in;
    float4*       out4 = (float4*)out;
    const int n4 = NTOT / 4;   // 7,077,888
    float m = -INFINITY;
    for (int i = blockIdx.x * blockDim.x + threadIdx.x; i < n4;
         i += gridDim.x * blockDim.x) {
        float4 v = in4[i];
        out4[i] = v;
        m = fmaxf(m, fmaxf(fmaxf(v.x, v.y), fmaxf(v.z, v.w)));
    }
    #pragma unroll
    for (int off = 32; off > 0; off >>= 1)
        m = fmaxf(m, __shfl_down(m, off, 64));
    __shared__ float smax[RED_THREADS / 64];
    const int lane = threadIdx.x & 63;
    const int wid  = threadIdx.x >> 6;
    if (lane == 0) smax[wid] = m;
    __syncthreads();
    if (threadIdx.x == 0) {
        float r = fmaxf(fmaxf(smax[0], smax[1]), fmaxf(smax[2], smax[3]));
        partial[blockIdx.x] = r;
    }
}

// Kernel 2: closed-form Bresenham rasterization. One thread per line step;
// grid = (chunk, crack, channel). For dx >= dy the x-advance fires every
// step (invariant 2*err > -dy), so step k paints (x0+sx*k, y0+sy*ck),
// ck = max(0, ceil((2k*dy-dx)/(2dx))); nsteps = max(dx,dy); the endpoint
// (k == nsteps) is NOT painted (done-after-move). Mirrored for dy > dx.
// Verified against the reference recurrence on (3,2),(4,1),(1,4),(5,3),
// (3,3),(2,1),(1,2),(n,0); passed rounds 2,4,5,8,9.
__global__ __launch_bounds__(PAINT_THREADS)
void paint_kernel(const int* __restrict__ x_start, const int* __restrict__ x_end,
                  const int* __restrict__ y_start, const int* __restrict__ y_end,
                  const int* __restrict__ length,  const int* __restrict__ width,
                  float* __restrict__ out, const float* __restrict__ partial) {
    const int b  = blockIdx.y;
    const int x0 = x_start[b], x1 = x_end[b];
    const int y0 = y_start[b], y1 = y_end[b];

    if (x0 == x1 && y0 == y1) return;          // done0: paints nothing

    const int dx = abs(x1 - x0), dy = abs(y1 - y0);
    const int nsteps = max(dx, dy);
    if ((int)(blockIdx.x * PAINT_THREADS) >= nsteps) return;  // block-uniform

    // Wave-redundant reduction of the 1024 partials (L2-resident); runs with
    // all 64 lanes active (shfl), so it precedes the per-lane k check.
    const int lane = threadIdx.x & 63;
    float m = -INFINITY;
    #pragma unroll
    for (int i = 0; i < RED_BLOCKS / 64; ++i) m = fmaxf(m, partial[lane + i * 64]);
    #pragma unroll
    for (int off = 32; off > 0; off >>= 1)
        m = fmaxf(m, __shfl_down(m, off, 64));
    const float val = __shfl(m, 0, 64);

    const int k = blockIdx.x * PAINT_THREADS + threadIdx.x;
    if (k >= nsteps) return;

    const int sx = (x0 < x1) ? 1 : -1;
    const int sy = (y0 < y1) ? 1 : -1;
    int X, Y;
    if (dx >= dy) {
        X = k;
        const int num = 2 * k * dy - dx;
        Y = (num <= 0) ? 0 : (num + 2 * dx - 1) / (2 * dx);
    } else {
        Y = k;
        const int num = 2 * k * dx - dy;
        X = (num <= 0) ? 0 : (num + 2 * dy - 1) / (2 * dy);
    }
    const int px = x0 + sx * X;
    const int py = y0 + sy * Y;

    // Clamped stamp bounds: no per-pixel divergent checks. 32-bit offsets.
    const int Wv = min(width[b],  N_COLS - py);
    const int Lv = min(length[b], N_ROWS - px);
    float* chan = out + blockIdx.z * NPIX;
    for (int dw = 0; dw < Wv; ++dw) {
        const int rowp = (py + dw) * N_ROWS + px;
        for (int dl = 0; dl < Lv; ++dl)
            chan[rowp + dl] = val;
    }
}

extern "C" void kernel_launch(void* const* d_in, const int* in_sizes, int n_in,
                              void* d_out, int out_size, void* d_ws, size_t ws_size,
                              hipStream_t stream) {
    const float* inp     = (const float*)d_in[0];
    const int*   x_start = (const int*)d_in[1];
    const int*   x_end   = (const int*)d_in[2];
    const int*   y_start = (const int*)d_in[3];
    const int*   y_end   = (const int*)d_in[4];
    const int*   length  = (const int*)d_in[5];
    const int*   width   = (const int*)d_in[6];
    float*       out     = (float*)d_out;
    float*       partial = (float*)d_ws;   // RED_BLOCKS floats

    copy_max_kernel<<<RED_BLOCKS, RED_THREADS, 0, stream>>>(inp, out, partial);
    dim3 pgrid(PAINT_CHUNKS, 64, N_CH);
    paint_kernel<<<pgrid, PAINT_THREADS, 0, stream>>>(
        x_start, x_end, y_start, y_end, length, width, out, partial);
}